// Round 3
// baseline (1371.977 us; speedup 1.0000x reference)
//
#include <hip/hip_runtime.h>

#define NF 64        // IN_F == HID_F == 64
#define BSH 6        // bucket shift: 64 nodes per bucket
#define BNODES 64

// ============ CSR build: two-level bucketed counting sort ============

__global__ void bucket_count(const int* __restrict__ dst, int* __restrict__ bcnt, int E) {
    int e = blockIdx.x * blockDim.x + threadIdx.x;
    if (e < E) atomicAdd(&bcnt[dst[e] >> BSH], 1);
}

// single block: exclusive scan of nb bucket counts (nb can exceed 256; chunked)
__global__ void scan_buckets(const int* __restrict__ bcnt, int* __restrict__ bbase,
                             int nb, int E, int* __restrict__ rowptr, int N) {
    __shared__ int s[256];
    __shared__ int run;
    int tid = threadIdx.x;
    if (tid == 0) run = 0;
    __syncthreads();
    for (int c = 0; c < nb; c += 256) {
        int i = c + tid;
        int v = (i < nb) ? bcnt[i] : 0;
        s[tid] = v; __syncthreads();
        for (int off = 1; off < 256; off <<= 1) {
            int t = (tid >= off) ? s[tid - off] : 0;
            __syncthreads();
            s[tid] += t;
            __syncthreads();
        }
        if (i < nb) bbase[i] = run + s[tid] - v;   // exclusive
        __syncthreads();
        if (tid == 255) run += s[255];
        __syncthreads();
    }
    if (tid == 0) { bbase[nb] = E; rowptr[N] = E; }
}

// scatter packed (dst_low<<20 | src) into bucket-contiguous regions
__global__ void bucket_scatter(const int* __restrict__ src, const int* __restrict__ dst,
                               const int* __restrict__ bbase, int* __restrict__ bcur,
                               int* __restrict__ tmp, int E) {
    int e = blockIdx.x * blockDim.x + threadIdx.x;
    if (e < E) {
        int d = dst[e];
        int b = d >> BSH;
        int pos = bbase[b] + atomicAdd(&bcur[b], 1);
        tmp[pos] = ((d & (BNODES - 1)) << 20) | src[e];
    }
}

// one block per bucket: 64-bin LDS counting sort -> rowptr, dinv, csr_src
__launch_bounds__(256)
__global__ void bucket_build(const int* __restrict__ tmp, const int* __restrict__ bbase,
                             int* __restrict__ csr_src, int* __restrict__ rowptr,
                             float* __restrict__ dinv, int N) {
    int b = blockIdx.x;
    int node0 = b << BSH;
    int beg = bbase[b], end = bbase[b + 1];
    __shared__ int cnt[BNODES], excl[BNODES], cur[BNODES];
    int tid = threadIdx.x;
    if (tid < BNODES) cnt[tid] = 0;
    __syncthreads();
    for (int e = beg + tid; e < end; e += 256)
        atomicAdd(&cnt[tmp[e] >> 20], 1);
    __syncthreads();
    if (tid == 0) {
        int run = 0;
#pragma unroll
        for (int i = 0; i < BNODES; ++i) { excl[i] = run; run += cnt[i]; }
    }
    __syncthreads();
    if (tid < BNODES) {
        int node = node0 + tid;
        if (node < N) {
            rowptr[node] = beg + excl[tid];
            dinv[node] = rsqrtf(fmaxf((float)cnt[tid], 1.0f));
        }
        cur[tid] = 0;
    }
    __syncthreads();
    for (int e = beg + tid; e < end; e += 256) {
        int v = tmp[e];
        int dlow = v >> 20;
        int pos = excl[dlow] + atomicAdd(&cur[dlow], 1);
        csr_src[beg + pos] = v & 0xFFFFF;
    }
}

// ============ SpMM as gather: one wave per dst node, lane = feature ============
// mode 1: out = -spmm(X)            (X1 recurrence, RE_NORM==1)
// mode 2: out = -2*spmm(X) - Xprev  (X2 recurrence)
__launch_bounds__(256)
__global__ void spmm_gather(const float* __restrict__ X, const int* __restrict__ rowptr,
                            const int* __restrict__ csr_src, const float* __restrict__ dinv,
                            const float* __restrict__ Xprev, float* __restrict__ out,
                            int n, int mode) {
    int node = (blockIdx.x * blockDim.x + threadIdx.x) >> 6;
    int f = threadIdx.x & 63;
    if (node >= n) return;
    int beg = rowptr[node];
    int end = rowptr[node + 1];
    float acc = 0.0f;
    int e = beg;
    for (; e + 4 <= end; e += 4) {
        int s0 = csr_src[e + 0];
        int s1 = csr_src[e + 1];
        int s2 = csr_src[e + 2];
        int s3 = csr_src[e + 3];
        float v0 = X[(size_t)s0 * NF + f] * dinv[s0];
        float v1 = X[(size_t)s1 * NF + f] * dinv[s1];
        float v2 = X[(size_t)s2 * NF + f] * dinv[s2];
        float v3 = X[(size_t)s3 * NF + f] * dinv[s3];
        acc += v0 + v1 + v2 + v3;
    }
    for (; e < end; ++e) {
        int s = csr_src[e];
        acc += X[(size_t)s * NF + f] * dinv[s];
    }
    float r;
    if (mode == 1) r = -acc * dinv[node];
    else           r = -2.0f * acc * dinv[node] - Xprev[(size_t)node * NF + f];
    out[(size_t)node * NF + f] = r;
}

// ============ GEMM: out[n, OUTF] = relu?([X0|X1|X2] @ W + b) ============
template <int OUTF>
__launch_bounds__(256)
__global__ void gemm_cheb(const float* __restrict__ X0, const float* __restrict__ X1,
                          const float* __restrict__ X2, const float* __restrict__ W,
                          const float* __restrict__ bias, float* __restrict__ out,
                          int n, int do_relu) {
    __shared__ float xs[256 * 65];
    const int tid = threadIdx.x;
    const int node0 = blockIdx.x * 256;
    const int node = node0 + tid;

    float acc[OUTF];
#pragma unroll
    for (int j = 0; j < OUTF; ++j) acc[j] = bias[j];

    const float* Xp[3] = {X0, X1, X2};
#pragma unroll 1
    for (int p = 0; p < 3; ++p) {
        const float* __restrict__ Xc = Xp[p];
#pragma unroll
        for (int j = 0; j < 16; ++j) {
            int idx4 = j * 256 + tid;
            int ln = idx4 >> 4;
            int k4 = (idx4 & 15) * 4;
            float4 v = make_float4(0.f, 0.f, 0.f, 0.f);
            int gnode = node0 + ln;
            if (gnode < n) v = *(const float4*)&Xc[(size_t)gnode * 64 + k4];
            float* s = &xs[ln * 65 + k4];
            s[0] = v.x; s[1] = v.y; s[2] = v.z; s[3] = v.w;
        }
        __syncthreads();

        const float* __restrict__ Wp = W + (size_t)p * 64 * OUTF;
        for (int k = 0; k < 64; ++k) {
            float x = xs[tid * 65 + k];
#pragma unroll
            for (int j = 0; j < OUTF; ++j)
                acc[j] += x * Wp[k * OUTF + j];
        }
        __syncthreads();
    }

    if (node < n) {
        float* o = &out[(size_t)node * OUTF];
#pragma unroll
        for (int j4 = 0; j4 < OUTF; j4 += 4) {
            float4 v;
            v.x = acc[j4 + 0]; v.y = acc[j4 + 1]; v.z = acc[j4 + 2]; v.w = acc[j4 + 3];
            if (do_relu) {
                v.x = fmaxf(v.x, 0.f); v.y = fmaxf(v.y, 0.f);
                v.z = fmaxf(v.z, 0.f); v.w = fmaxf(v.w, 0.f);
            }
            *(float4*)&o[j4] = v;
        }
    }
}

extern "C" void kernel_launch(void* const* d_in, const int* in_sizes, int n_in,
                              void* d_out, int out_size, void* d_ws, size_t ws_size,
                              hipStream_t stream) {
    const float* feat = (const float*)d_in[0];
    const int*   src  = (const int*)d_in[1];
    const int*   dst  = (const int*)d_in[2];
    const float* W1   = (const float*)d_in[3];
    const float* b1   = (const float*)d_in[4];
    const float* W2   = (const float*)d_in[5];
    const float* b2   = (const float*)d_in[6];
    float* out = (float*)d_out;

    const int N = in_sizes[0] / NF;   // 100000
    const int E = in_sizes[1];        // 1600000
    const size_t NFtot = (size_t)N * NF;
    const int nb = (N + BNODES - 1) >> BSH;   // 1563 buckets

    // workspace layout
    char* p = (char*)d_ws;
    int* bcnt    = (int*)p;     p += ((size_t)nb + 1) * 4;
    int* bcur    = (int*)p;     p += ((size_t)nb + 1) * 4;   // adjacent to bcnt: one memset
    int* bbase   = (int*)p;     p += ((size_t)nb + 1) * 4;
    int* rowptr  = (int*)p;     p += ((size_t)N + 256) * 4;
    int* csr_src = (int*)p;     p += (size_t)E * 4;
    float* dinv  = (float*)p;   p += ((size_t)N + 256) * 4;
    float* X1    = (float*)p;   p += NFtot * 4;
    float* X2    = (float*)p;   p += NFtot * 4;
    float* H     = (float*)p;   p += NFtot * 4;
    int* tmp = (int*)X1;        // packed edges; dead before X1 is first written

    const int TB = 256;
    dim3 blk(TB);
    dim3 gE((E + TB - 1) / TB);
    dim3 gWave(((size_t)N * 64 + TB - 1) / TB);
    dim3 gGemm((N + 255) / 256);

    // ---- CSR build ----
    hipMemsetAsync(bcnt, 0, 2 * ((size_t)nb + 1) * sizeof(int), stream);  // bcnt + bcur
    bucket_count<<<gE, blk, 0, stream>>>(dst, bcnt, E);
    scan_buckets<<<1, blk, 0, stream>>>(bcnt, bbase, nb, E, rowptr, N);
    bucket_scatter<<<gE, blk, 0, stream>>>(src, dst, bbase, bcur, tmp, E);
    bucket_build<<<dim3(nb), blk, 0, stream>>>(tmp, bbase, csr_src, rowptr, dinv, N);

    // ---- layer 1 ----
    spmm_gather<<<gWave, blk, 0, stream>>>(feat, rowptr, csr_src, dinv, nullptr, X1, N, 1);
    spmm_gather<<<gWave, blk, 0, stream>>>(X1, rowptr, csr_src, dinv, feat, X2, N, 2);
    gemm_cheb<64><<<gGemm, blk, 0, stream>>>(feat, X1, X2, W1, b1, H, N, 1);

    // ---- layer 2 ----
    spmm_gather<<<gWave, blk, 0, stream>>>(H, rowptr, csr_src, dinv, nullptr, X1, N, 1);
    spmm_gather<<<gWave, blk, 0, stream>>>(X1, rowptr, csr_src, dinv, H, X2, N, 2);
    gemm_cheb<32><<<gGemm, blk, 0, stream>>>(H, X1, X2, W2, b2, out, N, 0);
}

// Round 4
// 664.569 us; speedup vs baseline: 2.0645x; 2.0645x over previous
//
#include <hip/hip_runtime.h>

#define NF 64   // IN_F == HID_F == 64

// ============ CSR build (counting sort by dst) — round-2 proven version ============

__global__ void count_kernel(const int* __restrict__ dst, int* __restrict__ cnt, int E) {
    int e = blockIdx.x * blockDim.x + threadIdx.x;
    if (e < E) atomicAdd(&cnt[dst[e]], 1);
}

__global__ void block_sums(const int* __restrict__ cnt, int* __restrict__ blocksum, int n) {
    int tid = threadIdx.x;
    int base_i = blockIdx.x * 1024 + tid * 4;
    int t = 0;
#pragma unroll
    for (int j = 0; j < 4; ++j) t += (base_i + j < n) ? cnt[base_i + j] : 0;
    __shared__ int s[256];
    s[tid] = t; __syncthreads();
    for (int off = 128; off > 0; off >>= 1) {
        if (tid < off) s[tid] += s[tid + off];
        __syncthreads();
    }
    if (tid == 0) blocksum[blockIdx.x] = s[0];
}

__global__ void scan_blocksums(int* __restrict__ blocksum, int* __restrict__ rowptr,
                               int nb, int n) {
    int tid = threadIdx.x;
    int v = (tid < nb) ? blocksum[tid] : 0;
    __shared__ int s[256];
    s[tid] = v; __syncthreads();
    for (int off = 1; off < 256; off <<= 1) {
        int t = (tid >= off) ? s[tid - off] : 0;
        __syncthreads();
        s[tid] += t;
        __syncthreads();
    }
    if (tid < nb) blocksum[tid] = s[tid] - v;   // exclusive
    if (tid == 255) rowptr[n] = s[255];         // total == E
}

__global__ void scan_finalize(int* __restrict__ cnt, const int* __restrict__ blocksum,
                              int* __restrict__ rowptr, float* __restrict__ dinv, int n) {
    int tid = threadIdx.x;
    int base_i = blockIdx.x * 1024 + tid * 4;
    int v[4]; int tsum = 0;
#pragma unroll
    for (int j = 0; j < 4; ++j) { v[j] = (base_i + j < n) ? cnt[base_i + j] : 0; tsum += v[j]; }
    __shared__ int s[256];
    s[tid] = tsum; __syncthreads();
    for (int off = 1; off < 256; off <<= 1) {
        int t = (tid >= off) ? s[tid - off] : 0;
        __syncthreads();
        s[tid] += t;
        __syncthreads();
    }
    int base = blocksum[blockIdx.x] + (s[tid] - tsum);
#pragma unroll
    for (int j = 0; j < 4; ++j) {
        int i = base_i + j;
        if (i < n) {
            rowptr[i] = base;
            dinv[i] = rsqrtf(fmaxf((float)v[j], 1.0f));
            cnt[i] = 0;       // reused as cursor by fill_kernel
            base += v[j];
        }
    }
}

__global__ void fill_kernel(const int* __restrict__ src, const int* __restrict__ dst,
                            const int* __restrict__ rowptr, int* __restrict__ cursor,
                            int* __restrict__ csr_src, int E) {
    int e = blockIdx.x * blockDim.x + threadIdx.x;
    if (e < E) {
        int d = dst[e];
        int pos = rowptr[d] + atomicAdd(&cursor[d], 1);
        csr_src[pos] = src[e];
    }
}

// ============ SpMM gather v2: wave per dst node, 4 edges/iter via float4 ============
// 16-lane group g handles edge e+g; lane covers feats [4*(lane&15), +4).
// Cross-group __shfl_xor reduction at the end; group 0 stores the row.
// mode 1: out = -spmm(X)            (X1 recurrence, RE_NORM==1)
// mode 2: out = -2*spmm(X) - Xprev  (X2 recurrence)
__launch_bounds__(256)
__global__ void spmm_gather(const float* __restrict__ X, const int* __restrict__ rowptr,
                            const int* __restrict__ csr_src, const float* __restrict__ dinv,
                            const float* __restrict__ Xprev, float* __restrict__ out,
                            int n, int mode) {
    int node = (blockIdx.x * blockDim.x + threadIdx.x) >> 6;
    if (node >= n) return;
    int lane = threadIdx.x & 63;
    int g = lane >> 4;           // edge subgroup 0..3
    int fl = (lane & 15) << 2;   // feature offset 0,4,...,60

    int beg = rowptr[node];
    int end = rowptr[node + 1];
    float4 acc = make_float4(0.f, 0.f, 0.f, 0.f);
    for (int e0 = beg; e0 < end; e0 += 4) {
        int eg = e0 + g;
        if (eg < end) {
            int s = csr_src[eg];
            float dv = dinv[s];
            float4 v = *(const float4*)(X + (size_t)s * NF + fl);
            acc.x += v.x * dv; acc.y += v.y * dv;
            acc.z += v.z * dv; acc.w += v.w * dv;
        }
    }
    // reduce the 4 edge-subgroups (lanes differing in bits 4,5 share fl)
#pragma unroll
    for (int m = 16; m <= 32; m <<= 1) {
        acc.x += __shfl_xor(acc.x, m, 64);
        acc.y += __shfl_xor(acc.y, m, 64);
        acc.z += __shfl_xor(acc.z, m, 64);
        acc.w += __shfl_xor(acc.w, m, 64);
    }
    if (g == 0) {
        float dn = dinv[node];
        float4 r;
        if (mode == 1) {
            r.x = -acc.x * dn; r.y = -acc.y * dn;
            r.z = -acc.z * dn; r.w = -acc.w * dn;
        } else {
            float4 xp = *(const float4*)(Xprev + (size_t)node * NF + fl);
            r.x = -2.f * acc.x * dn - xp.x; r.y = -2.f * acc.y * dn - xp.y;
            r.z = -2.f * acc.z * dn - xp.z; r.w = -2.f * acc.w * dn - xp.w;
        }
        *(float4*)(out + (size_t)node * NF + fl) = r;
    }
}

// ============ GEMM: out[n, OUTF] = relu?([X0|X1|X2] @ W + b) ============
template <int OUTF>
__launch_bounds__(256)
__global__ void gemm_cheb(const float* __restrict__ X0, const float* __restrict__ X1,
                          const float* __restrict__ X2, const float* __restrict__ W,
                          const float* __restrict__ bias, float* __restrict__ out,
                          int n, int do_relu) {
    __shared__ float xs[256 * 65];
    const int tid = threadIdx.x;
    const int node0 = blockIdx.x * 256;
    const int node = node0 + tid;

    float acc[OUTF];
#pragma unroll
    for (int j = 0; j < OUTF; ++j) acc[j] = bias[j];

    const float* Xp[3] = {X0, X1, X2};
#pragma unroll 1
    for (int p = 0; p < 3; ++p) {
        const float* __restrict__ Xc = Xp[p];
#pragma unroll
        for (int j = 0; j < 16; ++j) {
            int idx4 = j * 256 + tid;
            int ln = idx4 >> 4;
            int k4 = (idx4 & 15) * 4;
            float4 v = make_float4(0.f, 0.f, 0.f, 0.f);
            int gnode = node0 + ln;
            if (gnode < n) v = *(const float4*)&Xc[(size_t)gnode * 64 + k4];
            float* s = &xs[ln * 65 + k4];
            s[0] = v.x; s[1] = v.y; s[2] = v.z; s[3] = v.w;
        }
        __syncthreads();

        const float* __restrict__ Wp = W + (size_t)p * 64 * OUTF;
        for (int k = 0; k < 64; ++k) {
            float x = xs[tid * 65 + k];
#pragma unroll
            for (int j = 0; j < OUTF; ++j)
                acc[j] += x * Wp[k * OUTF + j];
        }
        __syncthreads();
    }

    if (node < n) {
        float* o = &out[(size_t)node * OUTF];
#pragma unroll
        for (int j4 = 0; j4 < OUTF; j4 += 4) {
            float4 v;
            v.x = acc[j4 + 0]; v.y = acc[j4 + 1]; v.z = acc[j4 + 2]; v.w = acc[j4 + 3];
            if (do_relu) {
                v.x = fmaxf(v.x, 0.f); v.y = fmaxf(v.y, 0.f);
                v.z = fmaxf(v.z, 0.f); v.w = fmaxf(v.w, 0.f);
            }
            *(float4*)&o[j4] = v;
        }
    }
}

extern "C" void kernel_launch(void* const* d_in, const int* in_sizes, int n_in,
                              void* d_out, int out_size, void* d_ws, size_t ws_size,
                              hipStream_t stream) {
    const float* feat = (const float*)d_in[0];
    const int*   src  = (const int*)d_in[1];
    const int*   dst  = (const int*)d_in[2];
    const float* W1   = (const float*)d_in[3];
    const float* b1   = (const float*)d_in[4];
    const float* W2   = (const float*)d_in[5];
    const float* b2   = (const float*)d_in[6];
    float* out = (float*)d_out;

    const int N = in_sizes[0] / NF;   // 100000
    const int E = in_sizes[1];        // 1600000
    const size_t NFtot = (size_t)N * NF;

    // workspace layout (identical footprint to round 2)
    char* p = (char*)d_ws;
    int* cnt      = (int*)p;        p += ((size_t)N + 256) * 4;
    int* rowptr   = (int*)p;        p += ((size_t)N + 256) * 4;
    int* csr_src  = (int*)p;        p += (size_t)E * 4;
    int* blocksum = (int*)p;        p += 256 * 4;
    float* dinv   = (float*)p;      p += ((size_t)N + 256) * 4;
    float* X1     = (float*)p;      p += NFtot * 4;
    float* X2     = (float*)p;      p += NFtot * 4;
    float* H      = (float*)p;      p += NFtot * 4;

    const int TB = 256;
    dim3 blk(TB);
    dim3 gE((E + TB - 1) / TB);
    const int nb = (N + 1023) / 1024;   // 98 (must be <=256)
    dim3 gScan(nb);
    dim3 gWave(((size_t)N * 64 + TB - 1) / TB);
    dim3 gGemm((N + 255) / 256);

    // ---- CSR build ----
    hipMemsetAsync(cnt, 0, (size_t)N * sizeof(int), stream);
    count_kernel<<<gE, blk, 0, stream>>>(dst, cnt, E);
    block_sums<<<gScan, blk, 0, stream>>>(cnt, blocksum, N);
    scan_blocksums<<<1, blk, 0, stream>>>(blocksum, rowptr, nb, N);
    scan_finalize<<<gScan, blk, 0, stream>>>(cnt, blocksum, rowptr, dinv, N);
    fill_kernel<<<gE, blk, 0, stream>>>(src, dst, rowptr, cnt, csr_src, E);

    // ---- layer 1 ----
    spmm_gather<<<gWave, blk, 0, stream>>>(feat, rowptr, csr_src, dinv, nullptr, X1, N, 1);
    spmm_gather<<<gWave, blk, 0, stream>>>(X1, rowptr, csr_src, dinv, feat, X2, N, 2);
    gemm_cheb<64><<<gGemm, blk, 0, stream>>>(feat, X1, X2, W1, b1, H, N, 1);

    // ---- layer 2 ----
    spmm_gather<<<gWave, blk, 0, stream>>>(H, rowptr, csr_src, dinv, nullptr, X1, N, 1);
    spmm_gather<<<gWave, blk, 0, stream>>>(X1, rowptr, csr_src, dinv, H, X2, N, 2);
    gemm_cheb<32><<<gGemm, blk, 0, stream>>>(H, X1, X2, W2, b2, out, N, 0);
}

// Round 5
// 602.182 us; speedup vs baseline: 2.2783x; 1.1036x over previous
//
#include <hip/hip_runtime.h>

#define NF 64   // IN_F == HID_F == 64

typedef unsigned short u16;

__device__ __forceinline__ float bf2f(unsigned h) {
    return __uint_as_float(h << 16);
}
__device__ __forceinline__ u16 f2bf(float x) {   // round-to-nearest-even
    unsigned u = __float_as_uint(x);
    return (u16)((u + 0x7FFFu + ((u >> 16) & 1u)) >> 16);
}

// ============ CSR build (counting sort by dst) — round-2 proven version ============

__global__ void count_kernel(const int* __restrict__ dst, int* __restrict__ cnt, int E) {
    int e = blockIdx.x * blockDim.x + threadIdx.x;
    if (e < E) atomicAdd(&cnt[dst[e]], 1);
}

__global__ void block_sums(const int* __restrict__ cnt, int* __restrict__ blocksum, int n) {
    int tid = threadIdx.x;
    int base_i = blockIdx.x * 1024 + tid * 4;
    int t = 0;
#pragma unroll
    for (int j = 0; j < 4; ++j) t += (base_i + j < n) ? cnt[base_i + j] : 0;
    __shared__ int s[256];
    s[tid] = t; __syncthreads();
    for (int off = 128; off > 0; off >>= 1) {
        if (tid < off) s[tid] += s[tid + off];
        __syncthreads();
    }
    if (tid == 0) blocksum[blockIdx.x] = s[0];
}

__global__ void scan_blocksums(int* __restrict__ blocksum, int* __restrict__ rowptr,
                               int nb, int n) {
    int tid = threadIdx.x;
    int v = (tid < nb) ? blocksum[tid] : 0;
    __shared__ int s[256];
    s[tid] = v; __syncthreads();
    for (int off = 1; off < 256; off <<= 1) {
        int t = (tid >= off) ? s[tid - off] : 0;
        __syncthreads();
        s[tid] += t;
        __syncthreads();
    }
    if (tid < nb) blocksum[tid] = s[tid] - v;   // exclusive
    if (tid == 255) rowptr[n] = s[255];         // total == E
}

__global__ void scan_finalize(int* __restrict__ cnt, const int* __restrict__ blocksum,
                              int* __restrict__ rowptr, float* __restrict__ dinv, int n) {
    int tid = threadIdx.x;
    int base_i = blockIdx.x * 1024 + tid * 4;
    int v[4]; int tsum = 0;
#pragma unroll
    for (int j = 0; j < 4; ++j) { v[j] = (base_i + j < n) ? cnt[base_i + j] : 0; tsum += v[j]; }
    __shared__ int s[256];
    s[tid] = tsum; __syncthreads();
    for (int off = 1; off < 256; off <<= 1) {
        int t = (tid >= off) ? s[tid - off] : 0;
        __syncthreads();
        s[tid] += t;
        __syncthreads();
    }
    int base = blocksum[blockIdx.x] + (s[tid] - tsum);
#pragma unroll
    for (int j = 0; j < 4; ++j) {
        int i = base_i + j;
        if (i < n) {
            rowptr[i] = base;
            dinv[i] = rsqrtf(fmaxf((float)v[j], 1.0f));
            cnt[i] = 0;       // reused as cursor by fill_kernel
            base += v[j];
        }
    }
}

__global__ void fill_kernel(const int* __restrict__ src, const int* __restrict__ dst,
                            const int* __restrict__ rowptr, int* __restrict__ cursor,
                            int* __restrict__ csr_src, int E) {
    int e = blockIdx.x * blockDim.x + threadIdx.x;
    if (e < E) {
        int d = dst[e];
        int pos = rowptr[d] + atomicAdd(&cursor[d], 1);
        csr_src[pos] = src[e];
    }
}

// ============ prescale: Y = bf16(X * dinv[node]) ============
__global__ void prescale(const float* __restrict__ X, const float* __restrict__ dinv,
                         u16* __restrict__ Y, int total4) {   // total4 = N*16
    int i = blockIdx.x * blockDim.x + threadIdx.x;
    if (i < total4) {
        int node = i >> 4;
        float dn = dinv[node];
        float4 v = ((const float4*)X)[i];
        ushort4 y;
        y.x = f2bf(v.x * dn); y.y = f2bf(v.y * dn);
        y.z = f2bf(v.z * dn); y.w = f2bf(v.w * dn);
        ((ushort4*)Y)[i] = y;
    }
}

// ============ SpMM gather (bf16 rows): wave/node, 8 edges/iter, 16B loads ============
// Y holds bf16(X*dinv) rows. mode 1: Xout=-sum*dn, Yout=bf16(Xout*dn)
//                             mode 2: Xout=-2*sum*dn - Xprev
__launch_bounds__(256)
__global__ void spmm_bf16(const u16* __restrict__ Y, const int* __restrict__ rowptr,
                          const int* __restrict__ csr_src, const float* __restrict__ dinv,
                          const float* __restrict__ Xprev, float* __restrict__ Xout,
                          u16* __restrict__ Yout, int n, int mode) {
    int node = (blockIdx.x * blockDim.x + threadIdx.x) >> 6;
    if (node >= n) return;
    int lane = threadIdx.x & 63;
    int g = lane >> 3;            // edge subgroup 0..7
    int fl = (lane & 7) << 3;     // feature offset 0,8,...,56

    int beg = rowptr[node], end = rowptr[node + 1];
    float acc[8];
#pragma unroll
    for (int j = 0; j < 8; ++j) acc[j] = 0.f;

    for (int e0 = beg; e0 < end; e0 += 8) {
        int eg = e0 + g;
        if (eg < end) {
            int s = csr_src[eg];
            uint4 u = *(const uint4*)(Y + (size_t)s * NF + fl);
            acc[0] += bf2f(u.x & 0xFFFFu); acc[1] += bf2f(u.x >> 16);
            acc[2] += bf2f(u.y & 0xFFFFu); acc[3] += bf2f(u.y >> 16);
            acc[4] += bf2f(u.z & 0xFFFFu); acc[5] += bf2f(u.z >> 16);
            acc[6] += bf2f(u.w & 0xFFFFu); acc[7] += bf2f(u.w >> 16);
        }
    }
#pragma unroll
    for (int m = 8; m <= 32; m <<= 1) {
#pragma unroll
        for (int j = 0; j < 8; ++j) acc[j] += __shfl_xor(acc[j], m, 64);
    }
    if (g == 0) {
        float dn = dinv[node];
        float r[8];
        if (mode == 1) {
#pragma unroll
            for (int j = 0; j < 8; ++j) r[j] = -acc[j] * dn;
            uint4 uy;
            uy.x = (unsigned)f2bf(r[0] * dn) | ((unsigned)f2bf(r[1] * dn) << 16);
            uy.y = (unsigned)f2bf(r[2] * dn) | ((unsigned)f2bf(r[3] * dn) << 16);
            uy.z = (unsigned)f2bf(r[4] * dn) | ((unsigned)f2bf(r[5] * dn) << 16);
            uy.w = (unsigned)f2bf(r[6] * dn) | ((unsigned)f2bf(r[7] * dn) << 16);
            *(uint4*)(Yout + (size_t)node * NF + fl) = uy;
        } else {
            float4 a = *(const float4*)(Xprev + (size_t)node * NF + fl);
            float4 b = *(const float4*)(Xprev + (size_t)node * NF + fl + 4);
            r[0] = -2.f * acc[0] * dn - a.x; r[1] = -2.f * acc[1] * dn - a.y;
            r[2] = -2.f * acc[2] * dn - a.z; r[3] = -2.f * acc[3] * dn - a.w;
            r[4] = -2.f * acc[4] * dn - b.x; r[5] = -2.f * acc[5] * dn - b.y;
            r[6] = -2.f * acc[6] * dn - b.z; r[7] = -2.f * acc[7] * dn - b.w;
        }
        float4 o0 = make_float4(r[0], r[1], r[2], r[3]);
        float4 o1 = make_float4(r[4], r[5], r[6], r[7]);
        *(float4*)(Xout + (size_t)node * NF + fl) = o0;
        *(float4*)(Xout + (size_t)node * NF + fl + 4) = o1;
    }
}

// ============ GEMM: out = relu?([X0|X1|X2] @ W + b); optional Yout=bf16(out*dinv) ============
template <int OUTF>
__launch_bounds__(256)
__global__ void gemm_cheb(const float* __restrict__ X0, const float* __restrict__ X1,
                          const float* __restrict__ X2, const float* __restrict__ W,
                          const float* __restrict__ bias, float* __restrict__ out,
                          const float* __restrict__ dinv, u16* __restrict__ Yout,
                          int n, int do_relu) {
    __shared__ float xs[256 * 65];
    const int tid = threadIdx.x;
    const int node0 = blockIdx.x * 256;
    const int node = node0 + tid;

    float acc[OUTF];
#pragma unroll
    for (int j = 0; j < OUTF; ++j) acc[j] = bias[j];

    const float* Xp[3] = {X0, X1, X2};
#pragma unroll 1
    for (int p = 0; p < 3; ++p) {
        const float* __restrict__ Xc = Xp[p];
#pragma unroll
        for (int j = 0; j < 16; ++j) {
            int idx4 = j * 256 + tid;
            int ln = idx4 >> 4;
            int k4 = (idx4 & 15) * 4;
            float4 v = make_float4(0.f, 0.f, 0.f, 0.f);
            int gnode = node0 + ln;
            if (gnode < n) v = *(const float4*)&Xc[(size_t)gnode * 64 + k4];
            float* s = &xs[ln * 65 + k4];
            s[0] = v.x; s[1] = v.y; s[2] = v.z; s[3] = v.w;
        }
        __syncthreads();

        const float* __restrict__ Wp = W + (size_t)p * 64 * OUTF;
        for (int k = 0; k < 64; ++k) {
            float x = xs[tid * 65 + k];
#pragma unroll
            for (int j = 0; j < OUTF; ++j)
                acc[j] += x * Wp[k * OUTF + j];
        }
        __syncthreads();
    }

    if (node < n) {
        float dn = Yout ? dinv[node] : 0.f;
        float* o = &out[(size_t)node * OUTF];
#pragma unroll
        for (int j4 = 0; j4 < OUTF; j4 += 4) {
            float4 v;
            v.x = acc[j4 + 0]; v.y = acc[j4 + 1]; v.z = acc[j4 + 2]; v.w = acc[j4 + 3];
            if (do_relu) {
                v.x = fmaxf(v.x, 0.f); v.y = fmaxf(v.y, 0.f);
                v.z = fmaxf(v.z, 0.f); v.w = fmaxf(v.w, 0.f);
            }
            *(float4*)&o[j4] = v;
            if (Yout) {
                ushort4 y;
                y.x = f2bf(v.x * dn); y.y = f2bf(v.y * dn);
                y.z = f2bf(v.z * dn); y.w = f2bf(v.w * dn);
                *(ushort4*)&Yout[(size_t)node * OUTF + j4] = y;
            }
        }
    }
}

extern "C" void kernel_launch(void* const* d_in, const int* in_sizes, int n_in,
                              void* d_out, int out_size, void* d_ws, size_t ws_size,
                              hipStream_t stream) {
    const float* feat = (const float*)d_in[0];
    const int*   src  = (const int*)d_in[1];
    const int*   dst  = (const int*)d_in[2];
    const float* W1   = (const float*)d_in[3];
    const float* b1   = (const float*)d_in[4];
    const float* W2   = (const float*)d_in[5];
    const float* b2   = (const float*)d_in[6];
    float* out = (float*)d_out;

    const int N = in_sizes[0] / NF;   // 100000
    const int E = in_sizes[1];        // 1600000
    const size_t NFtot = (size_t)N * NF;

    // workspace layout (all chunks 16B-aligned)
    char* p = (char*)d_ws;
    int* cnt      = (int*)p;        p += ((size_t)N + 256) * 4;
    int* rowptr   = (int*)p;        p += ((size_t)N + 256) * 4;
    int* csr_src  = (int*)p;        p += (size_t)E * 4;
    int* blocksum = (int*)p;        p += 256 * 4;
    float* dinv   = (float*)p;      p += ((size_t)N + 256) * 4;
    float* X1     = (float*)p;      p += NFtot * 4;
    float* X2     = (float*)p;      p += NFtot * 4;
    float* H      = (float*)p;      p += NFtot * 4;
    u16* Ya       = (u16*)p;        p += NFtot * 2;   // Y0, later YH
    u16* Yb       = (u16*)p;        p += NFtot * 2;   // Y1 (both layers)

    const int TB = 256;
    dim3 blk(TB);
    dim3 gE((E + TB - 1) / TB);
    const int nb = (N + 1023) / 1024;   // 98 (must be <=256)
    dim3 gScan(nb);
    dim3 gWave(((size_t)N * 64 + TB - 1) / TB);
    dim3 gPre(((size_t)N * 16 + TB - 1) / TB);
    dim3 gGemm((N + 255) / 256);

    // ---- CSR build ----
    hipMemsetAsync(cnt, 0, (size_t)N * sizeof(int), stream);
    count_kernel<<<gE, blk, 0, stream>>>(dst, cnt, E);
    block_sums<<<gScan, blk, 0, stream>>>(cnt, blocksum, N);
    scan_blocksums<<<1, blk, 0, stream>>>(blocksum, rowptr, nb, N);
    scan_finalize<<<gScan, blk, 0, stream>>>(cnt, blocksum, rowptr, dinv, N);
    fill_kernel<<<gE, blk, 0, stream>>>(src, dst, rowptr, cnt, csr_src, E);

    // ---- layer 1 ----
    prescale<<<gPre, blk, 0, stream>>>(feat, dinv, Ya, (int)(N * 16));
    spmm_bf16<<<gWave, blk, 0, stream>>>(Ya, rowptr, csr_src, dinv, nullptr, X1, Yb, N, 1);
    spmm_bf16<<<gWave, blk, 0, stream>>>(Yb, rowptr, csr_src, dinv, feat, X2, nullptr, N, 2);
    gemm_cheb<64><<<gGemm, blk, 0, stream>>>(feat, X1, X2, W1, b1, H, dinv, Ya, N, 1);

    // ---- layer 2 ----
    spmm_bf16<<<gWave, blk, 0, stream>>>(Ya, rowptr, csr_src, dinv, nullptr, X1, Yb, N, 1);
    spmm_bf16<<<gWave, blk, 0, stream>>>(Yb, rowptr, csr_src, dinv, H, X2, nullptr, N, 2);
    gemm_cheb<32><<<gGemm, blk, 0, stream>>>(H, X1, X2, W2, b2, out, dinv, nullptr, N, 0);
}

// Round 6
// 561.954 us; speedup vs baseline: 2.4414x; 1.0716x over previous
//
#include <hip/hip_runtime.h>

#define NF 64   // IN_F == HID_F == 64
#define FILL_PASSES 8

typedef unsigned short u16;

__device__ __forceinline__ float bf2f(unsigned h) {
    return __uint_as_float(h << 16);
}
__device__ __forceinline__ u16 f2bf(float x) {   // round-to-nearest-even
    unsigned u = __float_as_uint(x);
    return (u16)((u + 0x7FFFu + ((u >> 16) & 1u)) >> 16);
}

// ============ CSR build (counting sort by dst) ============

__global__ void count_kernel(const int* __restrict__ dst, int* __restrict__ cnt, int E) {
    int e = blockIdx.x * blockDim.x + threadIdx.x;
    if (e < E) atomicAdd(&cnt[dst[e]], 1);
}

__global__ void block_sums(const int* __restrict__ cnt, int* __restrict__ blocksum, int n) {
    int tid = threadIdx.x;
    int base_i = blockIdx.x * 1024 + tid * 4;
    int t = 0;
#pragma unroll
    for (int j = 0; j < 4; ++j) t += (base_i + j < n) ? cnt[base_i + j] : 0;
    __shared__ int s[256];
    s[tid] = t; __syncthreads();
    for (int off = 128; off > 0; off >>= 1) {
        if (tid < off) s[tid] += s[tid + off];
        __syncthreads();
    }
    if (tid == 0) blocksum[blockIdx.x] = s[0];
}

__global__ void scan_blocksums(int* __restrict__ blocksum, int* __restrict__ rowptr,
                               int nb, int n) {
    int tid = threadIdx.x;
    int v = (tid < nb) ? blocksum[tid] : 0;
    __shared__ int s[256];
    s[tid] = v; __syncthreads();
    for (int off = 1; off < 256; off <<= 1) {
        int t = (tid >= off) ? s[tid - off] : 0;
        __syncthreads();
        s[tid] += t;
        __syncthreads();
    }
    if (tid < nb) blocksum[tid] = s[tid] - v;   // exclusive
    if (tid == 255) rowptr[n] = s[255];         // total == E
}

__global__ void scan_finalize(int* __restrict__ cnt, const int* __restrict__ blocksum,
                              int* __restrict__ rowptr, float* __restrict__ dinv, int n) {
    int tid = threadIdx.x;
    int base_i = blockIdx.x * 1024 + tid * 4;
    int v[4]; int tsum = 0;
#pragma unroll
    for (int j = 0; j < 4; ++j) { v[j] = (base_i + j < n) ? cnt[base_i + j] : 0; tsum += v[j]; }
    __shared__ int s[256];
    s[tid] = tsum; __syncthreads();
    for (int off = 1; off < 256; off <<= 1) {
        int t = (tid >= off) ? s[tid - off] : 0;
        __syncthreads();
        s[tid] += t;
        __syncthreads();
    }
    int base = blocksum[blockIdx.x] + (s[tid] - tsum);
#pragma unroll
    for (int j = 0; j < 4; ++j) {
        int i = base_i + j;
        if (i < n) {
            rowptr[i] = base;
            dinv[i] = rsqrtf(fmaxf((float)v[j], 1.0f));
            cnt[i] = 0;       // reused as cursor by fill_kernel
            base += v[j];
        }
    }
}

// multi-pass fill: pass p (from blockIdx) handles dst in [N*p/P, N*(p+1)/P)
// -> active csr/cursor region is L2-resident -> writes merge before eviction
__global__ void fill_kernel(const int* __restrict__ src, const int* __restrict__ dst,
                            const int* __restrict__ rowptr, int* __restrict__ cursor,
                            int* __restrict__ csr_src, int E, int N, int nchunks) {
    int b = blockIdx.x;
    int pass = b / nchunks;
    int chunk = b - pass * nchunks;
    int e = chunk * 256 + threadIdx.x;
    if (e >= E) return;
    int lo = (int)(((long long)N * pass) / FILL_PASSES);
    int hi = (int)(((long long)N * (pass + 1)) / FILL_PASSES);
    int d = dst[e];
    if (d >= lo && d < hi) {
        int pos = rowptr[d] + atomicAdd(&cursor[d], 1);
        csr_src[pos] = src[e];
    }
}

// ============ prescale: Y = bf16(X * dinv[node]) ============
__global__ void prescale(const float* __restrict__ X, const float* __restrict__ dinv,
                         u16* __restrict__ Y, int total4) {   // total4 = N*16
    int i = blockIdx.x * blockDim.x + threadIdx.x;
    if (i < total4) {
        int node = i >> 4;
        float dn = dinv[node];
        float4 v = ((const float4*)X)[i];
        ushort4 y;
        y.x = f2bf(v.x * dn); y.y = f2bf(v.y * dn);
        y.z = f2bf(v.z * dn); y.w = f2bf(v.w * dn);
        ((ushort4*)Y)[i] = y;
    }
}

// ============ SpMM gather (bf16 rows): wave/node, 8 edges/iter, 16B loads ============
__launch_bounds__(256)
__global__ void spmm_bf16(const u16* __restrict__ Y, const int* __restrict__ rowptr,
                          const int* __restrict__ csr_src, const float* __restrict__ dinv,
                          const float* __restrict__ Xprev, float* __restrict__ Xout,
                          u16* __restrict__ Yout, int n, int mode) {
    int node = (blockIdx.x * blockDim.x + threadIdx.x) >> 6;
    if (node >= n) return;
    int lane = threadIdx.x & 63;
    int g = lane >> 3;            // edge subgroup 0..7
    int fl = (lane & 7) << 3;     // feature offset 0,8,...,56

    int beg = rowptr[node], end = rowptr[node + 1];
    float acc[8];
#pragma unroll
    for (int j = 0; j < 8; ++j) acc[j] = 0.f;

    for (int e0 = beg; e0 < end; e0 += 8) {
        int eg = e0 + g;
        if (eg < end) {
            int s = csr_src[eg];
            uint4 u = *(const uint4*)(Y + (size_t)s * NF + fl);
            acc[0] += bf2f(u.x & 0xFFFFu); acc[1] += bf2f(u.x >> 16);
            acc[2] += bf2f(u.y & 0xFFFFu); acc[3] += bf2f(u.y >> 16);
            acc[4] += bf2f(u.z & 0xFFFFu); acc[5] += bf2f(u.z >> 16);
            acc[6] += bf2f(u.w & 0xFFFFu); acc[7] += bf2f(u.w >> 16);
        }
    }
#pragma unroll
    for (int m = 8; m <= 32; m <<= 1) {
#pragma unroll
        for (int j = 0; j < 8; ++j) acc[j] += __shfl_xor(acc[j], m, 64);
    }
    if (g == 0) {
        float dn = dinv[node];
        float r[8];
        if (mode == 1) {
#pragma unroll
            for (int j = 0; j < 8; ++j) r[j] = -acc[j] * dn;
            uint4 uy;
            uy.x = (unsigned)f2bf(r[0] * dn) | ((unsigned)f2bf(r[1] * dn) << 16);
            uy.y = (unsigned)f2bf(r[2] * dn) | ((unsigned)f2bf(r[3] * dn) << 16);
            uy.z = (unsigned)f2bf(r[4] * dn) | ((unsigned)f2bf(r[5] * dn) << 16);
            uy.w = (unsigned)f2bf(r[6] * dn) | ((unsigned)f2bf(r[7] * dn) << 16);
            *(uint4*)(Yout + (size_t)node * NF + fl) = uy;
        } else {
            float4 a = *(const float4*)(Xprev + (size_t)node * NF + fl);
            float4 b = *(const float4*)(Xprev + (size_t)node * NF + fl + 4);
            r[0] = -2.f * acc[0] * dn - a.x; r[1] = -2.f * acc[1] * dn - a.y;
            r[2] = -2.f * acc[2] * dn - a.z; r[3] = -2.f * acc[3] * dn - a.w;
            r[4] = -2.f * acc[4] * dn - b.x; r[5] = -2.f * acc[5] * dn - b.y;
            r[6] = -2.f * acc[6] * dn - b.z; r[7] = -2.f * acc[7] * dn - b.w;
        }
        float4 o0 = make_float4(r[0], r[1], r[2], r[3]);
        float4 o1 = make_float4(r[4], r[5], r[6], r[7]);
        *(float4*)(Xout + (size_t)node * NF + fl) = o0;
        *(float4*)(Xout + (size_t)node * NF + fl + 4) = o1;
    }
}

// ============ GEMM: 128 threads / 128 nodes per block; coalesced LDS-transposed epilogue ====
// out = relu?([X0|X1|X2] @ W + b); if OUTF==64 also Yout = bf16(out * dinv)
template <int OUTF>
__launch_bounds__(128)
__global__ void gemm_cheb(const float* __restrict__ X0, const float* __restrict__ X1,
                          const float* __restrict__ X2, const float* __restrict__ W,
                          const float* __restrict__ bias, float* __restrict__ out,
                          const float* __restrict__ dinv, u16* __restrict__ Yout,
                          int n, int do_relu) {
    __shared__ float xs[128 * 65];
    const int tid = threadIdx.x;
    const int node0 = blockIdx.x * 128;

    float acc[OUTF];
#pragma unroll
    for (int j = 0; j < OUTF; ++j) acc[j] = bias[j];

    const float* Xp[3] = {X0, X1, X2};
#pragma unroll 1
    for (int p = 0; p < 3; ++p) {
        const float* __restrict__ Xc = Xp[p];
        // stage 128 node-rows (64 floats each): 2048 float4 / 128 threads = 16 iters
#pragma unroll
        for (int j = 0; j < 16; ++j) {
            int idx4 = j * 128 + tid;
            int ln = idx4 >> 4;
            int k4 = (idx4 & 15) * 4;
            float4 v = make_float4(0.f, 0.f, 0.f, 0.f);
            int gnode = node0 + ln;
            if (gnode < n) v = *(const float4*)&Xc[(size_t)gnode * 64 + k4];
            float* s = &xs[ln * 65 + k4];
            s[0] = v.x; s[1] = v.y; s[2] = v.z; s[3] = v.w;
        }
        __syncthreads();

        const float* __restrict__ Wp = W + (size_t)p * 64 * OUTF;
        for (int k = 0; k < 64; ++k) {
            float x = xs[tid * 65 + k];
#pragma unroll
            for (int j = 0; j < OUTF; ++j)
                acc[j] += x * Wp[k * OUTF + j];
        }
        __syncthreads();
    }

    // ---- epilogue: acc -> LDS (padded) -> coalesced global stores ----
    const int ST = OUTF + 1;   // 65 or 33
#pragma unroll
    for (int j = 0; j < OUTF; ++j) {
        float v = acc[j];
        if (do_relu) v = fmaxf(v, 0.f);
        xs[tid * ST + j] = v;
    }
    __syncthreads();

    if (OUTF == 64) {
#pragma unroll
        for (int j = 0; j < 16; ++j) {
            int idx4 = j * 128 + tid;
            int ln = idx4 >> 4;
            int k4 = (idx4 & 15) * 4;
            int gnode = node0 + ln;
            if (gnode < n) {
                const float* s = &xs[ln * 65 + k4];
                float4 v = make_float4(s[0], s[1], s[2], s[3]);
                *(float4*)&out[(size_t)gnode * 64 + k4] = v;
                if (Yout) {
                    float dn = dinv[gnode];
                    ushort4 y;
                    y.x = f2bf(v.x * dn); y.y = f2bf(v.y * dn);
                    y.z = f2bf(v.z * dn); y.w = f2bf(v.w * dn);
                    *(ushort4*)&Yout[(size_t)gnode * 64 + k4] = y;
                }
            }
        }
    } else {   // OUTF == 32
#pragma unroll
        for (int j = 0; j < 8; ++j) {
            int idx4 = j * 128 + tid;
            int ln = idx4 >> 3;
            int k4 = (idx4 & 7) * 4;
            int gnode = node0 + ln;
            if (gnode < n) {
                const float* s = &xs[ln * 33 + k4];
                *(float4*)&out[(size_t)gnode * 32 + k4] =
                    make_float4(s[0], s[1], s[2], s[3]);
            }
        }
    }
}

extern "C" void kernel_launch(void* const* d_in, const int* in_sizes, int n_in,
                              void* d_out, int out_size, void* d_ws, size_t ws_size,
                              hipStream_t stream) {
    const float* feat = (const float*)d_in[0];
    const int*   src  = (const int*)d_in[1];
    const int*   dst  = (const int*)d_in[2];
    const float* W1   = (const float*)d_in[3];
    const float* b1   = (const float*)d_in[4];
    const float* W2   = (const float*)d_in[5];
    const float* b2   = (const float*)d_in[6];
    float* out = (float*)d_out;

    const int N = in_sizes[0] / NF;   // 100000
    const int E = in_sizes[1];        // 1600000
    const size_t NFtot = (size_t)N * NF;

    // workspace layout (all chunks 16B-aligned)
    char* p = (char*)d_ws;
    int* cnt      = (int*)p;        p += ((size_t)N + 256) * 4;
    int* rowptr   = (int*)p;        p += ((size_t)N + 256) * 4;
    int* csr_src  = (int*)p;        p += (size_t)E * 4;
    int* blocksum = (int*)p;        p += 256 * 4;
    float* dinv   = (float*)p;      p += ((size_t)N + 256) * 4;
    float* X1     = (float*)p;      p += NFtot * 4;
    float* X2     = (float*)p;      p += NFtot * 4;
    float* H      = (float*)p;      p += NFtot * 4;
    u16* Ya       = (u16*)p;        p += NFtot * 2;   // Y0, later YH
    u16* Yb       = (u16*)p;        p += NFtot * 2;   // Y1 (both layers)

    const int TB = 256;
    dim3 blk(TB);
    dim3 gE((E + TB - 1) / TB);
    const int nchunks = (E + TB - 1) / TB;            // 6250
    dim3 gFill(nchunks * FILL_PASSES);
    const int nb = (N + 1023) / 1024;   // 98 (must be <=256)
    dim3 gScan(nb);
    dim3 gWave(((size_t)N * 64 + TB - 1) / TB);
    dim3 gPre(((size_t)N * 16 + TB - 1) / TB);
    dim3 gGemm((N + 127) / 128);
    dim3 blk128(128);

    // ---- CSR build ----
    hipMemsetAsync(cnt, 0, (size_t)N * sizeof(int), stream);
    count_kernel<<<gE, blk, 0, stream>>>(dst, cnt, E);
    block_sums<<<gScan, blk, 0, stream>>>(cnt, blocksum, N);
    scan_blocksums<<<1, blk, 0, stream>>>(blocksum, rowptr, nb, N);
    scan_finalize<<<gScan, blk, 0, stream>>>(cnt, blocksum, rowptr, dinv, N);
    fill_kernel<<<gFill, blk, 0, stream>>>(src, dst, rowptr, cnt, csr_src, E, N, nchunks);

    // ---- layer 1 ----
    prescale<<<gPre, blk, 0, stream>>>(feat, dinv, Ya, (int)(N * 16));
    spmm_bf16<<<gWave, blk, 0, stream>>>(Ya, rowptr, csr_src, dinv, nullptr, X1, Yb, N, 1);
    spmm_bf16<<<gWave, blk, 0, stream>>>(Yb, rowptr, csr_src, dinv, feat, X2, nullptr, N, 2);
    gemm_cheb<64><<<gGemm, blk128, 0, stream>>>(feat, X1, X2, W1, b1, H, dinv, Ya, N, 1);

    // ---- layer 2 ----
    spmm_bf16<<<gWave, blk, 0, stream>>>(Ya, rowptr, csr_src, dinv, nullptr, X1, Yb, N, 1);
    spmm_bf16<<<gWave, blk, 0, stream>>>(Yb, rowptr, csr_src, dinv, H, X2, nullptr, N, 2);
    gemm_cheb<32><<<gGemm, blk128, 0, stream>>>(H, X1, X2, W2, b2, out, dinv, nullptr, N, 0);
}